// Round 2
// baseline (1054.689 us; speedup 1.0000x reference)
//
#include <hip/hip_runtime.h>
#include <hip/hip_bf16.h>

#define B_   2
#define L_   2048
#define DIM_ 512
#define NH_  8
#define HD_  64
#define R_   8
#define EH_  16
#define T_   2

__device__ __forceinline__ float gelu_f(float x){
  return 0.5f * x * (1.0f + erff(x * 0.70710678118654752f));
}
__device__ __forceinline__ float softplus_f(float x){
  return (x > 20.f) ? x : log1pf(expf(x));
}

// ---------------------------------------------------------------------------
// k_misc: build Wt[h][d][17][8] (l2_w transposed + bias row), eta, rope tables,
//         init edge tables to -1.
// ---------------------------------------------------------------------------
__global__ __launch_bounds__(256) void k_misc(
    const float* __restrict__ l2w, const float* __restrict__ l2b,
    const float* __restrict__ step,
    float* __restrict__ Wt, float* __restrict__ eta,
    float* __restrict__ ropeC, float* __restrict__ ropeS,
    int* __restrict__ esrc, int* __restrict__ edst)
{
  int idx = blockIdx.x * 256 + threadIdx.x;
  if (idx < NH_*HD_*17*R_){
    int r  = idx & 7;
    int k  = (idx >> 3) % 17;
    int hd = idx / 136;          // h*64 + d
    int d  = hd & 63, h = hd >> 6;
    int col = h*512 + r*64 + d;
    Wt[idx] = (k < 16) ? l2w[k*4096 + col] : l2b[col];
    return;
  }
  idx -= NH_*HD_*17*R_;
  if (idx < T_*L_){ eta[idx] = softplus_f(step[idx]); return; }
  idx -= T_*L_;
  if (idx < 9*32){
    int d = idx & 31, rel = (idx >> 5) - 4;
    float invf = expf(-((float)d / 32.f) * 9.210340371976184f);  // ln(10000)
    float ang = (float)rel * invf;
    ropeC[idx] = cosf(ang); ropeS[idx] = sinf(ang);
    return;
  }
  idx -= 9*32;
  if (idx < 2*8*L_){
    if (idx < 8*L_) esrc[idx] = -1; else edst[idx - 8*L_] = -1;
    return;
  }
}

// ---------------------------------------------------------------------------
// k_fill: scatter edge ids into per-node slot tables (unique (node,slot)).
// ---------------------------------------------------------------------------
__global__ __launch_bounds__(256) void k_fill(
    const int* __restrict__ ei, const int* __restrict__ ej, int E,
    int* __restrict__ esrc, int* __restrict__ edst)
{
  int e = blockIdx.x * 256 + threadIdx.x;
  if (e >= E) return;
  int i = ei[e], j = ej[e];
  int o = j - i;                      // in [-4,4] \ {0}
  int slot = (o < 0) ? (o + 4) : (o + 3);
  esrc[slot*L_ + i] = e;
  edst[slot*L_ + j] = e;
}

// ---------------------------------------------------------------------------
// k_te: u[(b*512 + n)*2048 + l] = x[b,l,:] @ te_w[:,n] + te_b[n]   (d-major u)
// 64x64 tile, BK=16, 256 threads, 4x4 per thread.
// ---------------------------------------------------------------------------
__global__ __launch_bounds__(256) void k_te(
    const float* __restrict__ x, const float* __restrict__ w,
    const float* __restrict__ bias, float* __restrict__ u)
{
  __shared__ float As[16][64];
  __shared__ float Bs[16][64];
  const int m0 = blockIdx.x * 64;
  const int n0 = blockIdx.y * 64;
  const int tid = threadIdx.x;
  const int ty = tid >> 4, tx = tid & 15;
  float acc[4][4] = {};
  for (int k0 = 0; k0 < 512; k0 += 16){
    {
      int m = tid >> 2, seg = tid & 3;
      float4 v = *(const float4*)(x + (size_t)(m0 + m)*512 + k0 + seg*4);
      As[seg*4+0][m] = v.x; As[seg*4+1][m] = v.y;
      As[seg*4+2][m] = v.z; As[seg*4+3][m] = v.w;
    }
    {
      int k = tid >> 4, c = (tid & 15)*4;
      float4 v = *(const float4*)(w + (size_t)(k0 + k)*512 + n0 + c);
      *(float4*)&Bs[k][c] = v;
    }
    __syncthreads();
    #pragma unroll
    for (int k = 0; k < 16; k++){
      float4 a = *(const float4*)(&As[k][ty*4]);
      float4 b = *(const float4*)(&Bs[k][tx*4]);
      float av[4] = {a.x, a.y, a.z, a.w};
      float bv[4] = {b.x, b.y, b.z, b.w};
      #pragma unroll
      for (int ii = 0; ii < 4; ii++)
        #pragma unroll
        for (int jj = 0; jj < 4; jj++)
          acc[ii][jj] = fmaf(av[ii], bv[jj], acc[ii][jj]);
    }
    __syncthreads();
  }
  const int bb = m0 >> 11;
  const int lb = (m0 & 2047) + ty*4;
  #pragma unroll
  for (int jj = 0; jj < 4; jj++){
    int n = n0 + tx*4 + jj;
    float bv = bias[n];
    float4 o;
    o.x = acc[0][jj] + bv; o.y = acc[1][jj] + bv;
    o.z = acc[2][jj] + bv; o.w = acc[3][jj] + bv;
    *(float4*)&u[((size_t)(bb*512 + n))*2048 + lb] = o;
  }
}

// ---------------------------------------------------------------------------
// k_feat: per (b, edge): alphas and h2 (edge MLPs, EH=16), thread = edge.
// ---------------------------------------------------------------------------
__global__ __launch_bounds__(256) void k_feat(
    const float* __restrict__ x, const int* __restrict__ ei, const int* __restrict__ ej,
    const float* __restrict__ a1w, const float* __restrict__ l1w,
    const float* __restrict__ a1b, const float* __restrict__ a2w,
    const float* __restrict__ a2b, const float* __restrict__ l1b,
    int E, float* __restrict__ alphas, float* __restrict__ h2t)
{
  int e = blockIdx.x * 256 + threadIdx.x;
  int b = blockIdx.y;
  if (e >= E) return;
  int i = ei[e], j = ej[e];
  const float4* xi = (const float4*)(x + ((size_t)b*L_ + i)*DIM_);
  const float4* xj = (const float4*)(x + ((size_t)b*L_ + j)*DIM_);
  float ha[16] = {}, hl[16] = {};
  #pragma unroll 4
  for (int kk = 0; kk < 256; kk++){
    float4 v = (kk < 128) ? xi[kk] : xj[kk - 128];
    const float* w1 = a1w + kk*64;
    const float* w2 = l1w + kk*64;
    #pragma unroll
    for (int n = 0; n < 16; n++){
      ha[n] += v.x*w1[n] + v.y*w1[16+n] + v.z*w1[32+n] + v.w*w1[48+n];
      hl[n] += v.x*w2[n] + v.y*w2[16+n] + v.z*w2[32+n] + v.w*w2[48+n];
    }
  }
  float av = a2b[0];
  #pragma unroll
  for (int n = 0; n < 16; n++){
    float g = gelu_f(ha[n] + a1b[n]);
    av += g * a2w[n];
  }
  alphas[(size_t)b*E + e] = softplus_f(av);
  #pragma unroll
  for (int n = 0; n < 16; n++){
    float g = gelu_f(hl[n] + l1b[n]);
    h2t[((size_t)b*16 + n)*E + e] = g;
  }
}

// ---------------------------------------------------------------------------
// k_edge: per (b,h,edge) residual. Thread = edge; Λ rows recomputed from
// h2 (17x8 FMAs per d, wave-uniform W → s_loads). Pass1 accumulates S[r]
// (and row norms at t=0); pass2 recomputes lam and writes residuals.
// ---------------------------------------------------------------------------
template<int TZERO>
__global__ __launch_bounds__(256) void k_edge(
    const float* __restrict__ u, const float* __restrict__ Wt,
    const float* __restrict__ h2t, const float* __restrict__ alphas,
    const float* __restrict__ ropeC, const float* __restrict__ ropeS,
    const int* __restrict__ ei, const int* __restrict__ ej,
    int E, float* __restrict__ invn, float* __restrict__ res)
{
  int e = blockIdx.x * 256 + threadIdx.x;
  int bh = blockIdx.y;
  int b = bh >> 3, h = bh & 7;
  if (e >= E) return;
  int i = ei[e], j = ej[e];
  int ridx = (i - j) + 4;
  const float* cT = ropeC + ridx*32;
  const float* sT = ropeS + ridx*32;
  const float* ub = u + ((size_t)(b*512 + h*64))*2048;
  const float* Wh = Wt + (size_t)h*(64*136);
  float h2v[16];
  #pragma unroll
  for (int k = 0; k < 16; k++) h2v[k] = h2t[((size_t)b*16 + k)*E + e];

  float S[8] = {};
  float ss[8] = {};
  #pragma unroll 2
  for (int dp = 0; dp < 32; dp++){
    float ui0 = ub[dp*2048 + i];
    float ui1 = ub[(dp+32)*2048 + i];
    float uj0 = ub[dp*2048 + j];
    float uj1 = ub[(dp+32)*2048 + j];
    float c = cT[dp], s = sT[dp];
    float d0 = ui0*c - ui1*s - uj0;
    float d1 = ui1*c + ui0*s - uj1;
    const float* W0 = Wh + dp*136;
    const float* W1 = Wh + (dp+32)*136;
    float lam0[8], lam1[8];
    #pragma unroll
    for (int r = 0; r < 8; r++){ lam0[r] = W0[128+r]; lam1[r] = W1[128+r]; }
    #pragma unroll
    for (int k = 0; k < 16; k++){
      float hk = h2v[k];
      #pragma unroll
      for (int r = 0; r < 8; r++){
        lam0[r] = fmaf(W0[k*8+r], hk, lam0[r]);
        lam1[r] = fmaf(W1[k*8+r], hk, lam1[r]);
      }
    }
    #pragma unroll
    for (int r = 0; r < 8; r++){
      S[r] += lam0[r]*d0 + lam1[r]*d1;
      if (TZERO) ss[r] += lam0[r]*lam0[r] + lam1[r]*lam1[r];
    }
  }

  float alpha = alphas[(size_t)b*E + e];
  float coef[8];
  #pragma unroll
  for (int r = 0; r < 8; r++){
    float iv;
    if (TZERO){
      iv = 1.f / fmaxf(sqrtf(ss[r]), 1e-12f);
      invn[((size_t)bh*8 + r)*E + e] = iv;
    } else {
      iv = invn[((size_t)bh*8 + r)*E + e];
    }
    coef[r] = iv * iv * S[r];
  }

  float* rr = res + (size_t)bh*64*E;
  #pragma unroll 2
  for (int dp = 0; dp < 32; dp++){
    float ui0 = ub[dp*2048 + i];
    float ui1 = ub[(dp+32)*2048 + i];
    float uj0 = ub[dp*2048 + j];
    float uj1 = ub[(dp+32)*2048 + j];
    float c = cT[dp], s = sT[dp];
    float d0 = ui0*c - ui1*s - uj0;
    float d1 = ui1*c + ui0*s - uj1;
    const float* W0 = Wh + dp*136;
    const float* W1 = Wh + (dp+32)*136;
    float lam0[8], lam1[8];
    #pragma unroll
    for (int r = 0; r < 8; r++){ lam0[r] = W0[128+r]; lam1[r] = W1[128+r]; }
    #pragma unroll
    for (int k = 0; k < 16; k++){
      float hk = h2v[k];
      #pragma unroll
      for (int r = 0; r < 8; r++){
        lam0[r] = fmaf(W0[k*8+r], hk, lam0[r]);
        lam1[r] = fmaf(W1[k*8+r], hk, lam1[r]);
      }
    }
    float r0 = alpha*d0, r1 = alpha*d1;
    #pragma unroll
    for (int r = 0; r < 8; r++){
      r0 = fmaf(coef[r], lam0[r], r0);
      r1 = fmaf(coef[r], lam1[r], r1);
    }
    rr[(size_t)dp*E + e]       = r0;
    rr[(size_t)(dp+32)*E + e]  = r1;
  }
}

// ---------------------------------------------------------------------------
// k_upd: per node, gather +res over src edges, -res over dst edges, apply eta.
// ---------------------------------------------------------------------------
__global__ __launch_bounds__(256) void k_upd(
    int t, const float* __restrict__ res, const int* __restrict__ esrc,
    const int* __restrict__ edst, const float* __restrict__ eta,
    int E, float* __restrict__ u)
{
  int bh = blockIdx.y;
  int l  = blockIdx.x*64 + (threadIdx.x & 63);
  int dg = threadIdx.x >> 6;
  int es[8], ed[8];
  #pragma unroll
  for (int o = 0; o < 8; o++){ es[o] = esrc[o*L_ + l]; ed[o] = edst[o*L_ + l]; }
  float et = eta[t*L_ + l];
  const float* rr = res + (size_t)bh*64*E;
  float* ub = u + (size_t)bh*64*2048;
  for (int d = dg*16; d < dg*16 + 16; d++){
    const float* rd = rr + (size_t)d*E;
    float acc = 0.f;
    #pragma unroll
    for (int o = 0; o < 8; o++){
      float vs = (es[o] >= 0) ? rd[es[o]] : 0.f;
      float vd = (ed[o] >= 0) ? rd[ed[o]] : 0.f;
      acc += vs - vd;
    }
    ub[(size_t)d*2048 + l] -= et * acc;
  }
}

// ---------------------------------------------------------------------------
// k_out: out[b,l,n] = u[b,:,l] @ out_w[:,n] + out_b[n], f32 store.
// ---------------------------------------------------------------------------
__global__ __launch_bounds__(256) void k_out(
    const float* __restrict__ u, const float* __restrict__ w,
    const float* __restrict__ bias, float* __restrict__ outp)
{
  __shared__ float As[16][64];
  __shared__ float Bs[16][64];
  const int m0 = blockIdx.x * 64;
  const int n0 = blockIdx.y * 64;
  const int tid = threadIdx.x;
  const int ty = tid >> 4, tx = tid & 15;
  const int bb = m0 >> 11;
  const int l0 = m0 & 2047;
  float acc[4][4] = {};
  for (int k0 = 0; k0 < 512; k0 += 16){
    {
      int k = tid >> 4, ls = (tid & 15)*4;
      float4 v = *(const float4*)&u[((size_t)(bb*512 + k0 + k))*2048 + l0 + ls];
      *(float4*)&As[k][ls] = v;
    }
    {
      int k = tid >> 4, c = (tid & 15)*4;
      float4 v = *(const float4*)(w + (size_t)(k0 + k)*512 + n0 + c);
      *(float4*)&Bs[k][c] = v;
    }
    __syncthreads();
    #pragma unroll
    for (int k = 0; k < 16; k++){
      float4 a = *(const float4*)(&As[k][ty*4]);
      float4 b = *(const float4*)(&Bs[k][tx*4]);
      float av[4] = {a.x, a.y, a.z, a.w};
      float bv[4] = {b.x, b.y, b.z, b.w};
      #pragma unroll
      for (int ii = 0; ii < 4; ii++)
        #pragma unroll
        for (int jj = 0; jj < 4; jj++)
          acc[ii][jj] = fmaf(av[ii], bv[jj], acc[ii][jj]);
    }
    __syncthreads();
  }
  float bv[4];
  #pragma unroll
  for (int jj = 0; jj < 4; jj++) bv[jj] = bias[n0 + tx*4 + jj];
  #pragma unroll
  for (int ii = 0; ii < 4; ii++){
    int l = l0 + ty*4 + ii;
    float4 o;
    o.x = acc[ii][0] + bv[0];
    o.y = acc[ii][1] + bv[1];
    o.z = acc[ii][2] + bv[2];
    o.w = acc[ii][3] + bv[3];
    *(float4*)&outp[((size_t)(bb*2048 + l))*512 + n0 + tx*4] = o;
  }
}

// ---------------------------------------------------------------------------
extern "C" void kernel_launch(void* const* d_in, const int* in_sizes, int n_in,
                              void* d_out, int out_size, void* d_ws, size_t ws_size,
                              hipStream_t stream)
{
  const float* x    = (const float*)d_in[0];
  const int*   ei   = (const int*)d_in[1];
  const int*   ej   = (const int*)d_in[2];
  const float* tew  = (const float*)d_in[3];
  const float* teb  = (const float*)d_in[4];
  const float* a1w  = (const float*)d_in[5];
  const float* a1b  = (const float*)d_in[6];
  const float* a2w  = (const float*)d_in[7];
  const float* a2b  = (const float*)d_in[8];
  const float* l1w  = (const float*)d_in[9];
  const float* l1b  = (const float*)d_in[10];
  const float* l2w  = (const float*)d_in[11];
  const float* l2b  = (const float*)d_in[12];
  const float* step = (const float*)d_in[13];
  const float* ow   = (const float*)d_in[14];
  const float* ob   = (const float*)d_in[15];
  float* outp = (float*)d_out;
  const int E = in_sizes[1];

  char* p = (char*)d_ws;
  auto carve = [&](size_t nbytes)->char*{
    char* q = p; p += (nbytes + 255) & ~(size_t)255; return q;
  };
  float* u      = (float*)carve((size_t)B_*512*2048*4);     // d-major node states
  float* res    = (float*)carve((size_t)B_*NH_*64*E*4);     // per-edge residuals
  float* h2t    = (float*)carve((size_t)B_*16*E*4);
  float* alphas = (float*)carve((size_t)B_*E*4);
  float* invn   = (float*)carve((size_t)B_*NH_*8*E*4);
  float* Wt     = (float*)carve((size_t)69632*4);
  float* eta    = (float*)carve((size_t)T_*L_*4);
  float* ropeC  = (float*)carve((size_t)288*4);
  float* ropeS  = (float*)carve((size_t)288*4);
  int*   esrc   = (int*)carve((size_t)8*L_*4);
  int*   edst   = (int*)carve((size_t)8*L_*4);

  k_misc<<<dim3(418), dim3(256), 0, stream>>>(l2w, l2b, step,
                                              Wt, eta, ropeC, ropeS, esrc, edst);
  k_fill<<<dim3((E + 255)/256), dim3(256), 0, stream>>>(ei, ej, E, esrc, edst);
  k_te<<<dim3(64, 8), dim3(256), 0, stream>>>(x, tew, teb, u);
  k_feat<<<dim3((E + 255)/256, B_), dim3(256), 0, stream>>>(
      x, ei, ej, a1w, l1w, a1b, a2w, a2b, l1b, E, alphas, h2t);

  for (int t = 0; t < T_; t++){
    if (t == 0)
      k_edge<1><<<dim3((E + 255)/256, B_*NH_), dim3(256), 0, stream>>>(
          u, Wt, h2t, alphas, ropeC, ropeS, ei, ej, E, invn, res);
    else
      k_edge<0><<<dim3((E + 255)/256, B_*NH_), dim3(256), 0, stream>>>(
          u, Wt, h2t, alphas, ropeC, ropeS, ei, ej, E, invn, res);
    k_upd<<<dim3(L_/64, B_*NH_), dim3(256), 0, stream>>>(t, res, esrc, edst, eta, E, u);
  }

  k_out<<<dim3(64, 8), dim3(256), 0, stream>>>(u, ow, ob, outp);
}

// Round 3
// 590.579 us; speedup vs baseline: 1.7859x; 1.7859x over previous
//
#include <hip/hip_runtime.h>
#include <hip/hip_bf16.h>

#define B_   2
#define L_   2048
#define DIM_ 512
#define NH_  8
#define HD_  64
#define R_   8
#define EH_  16
#define T_   2

__device__ __forceinline__ float gelu_f(float x){
  return 0.5f * x * (1.0f + erff(x * 0.70710678118654752f));
}
__device__ __forceinline__ float softplus_f(float x){
  return (x > 20.f) ? x : log1pf(expf(x));
}

// ---------------------------------------------------------------------------
// k_misc: build Wt[h][d][17][8] (l2_w transposed + bias row), eta, rope tables,
//         init edge tables to -1.
// ---------------------------------------------------------------------------
__global__ __launch_bounds__(256) void k_misc(
    const float* __restrict__ l2w, const float* __restrict__ l2b,
    const float* __restrict__ step,
    float* __restrict__ Wt, float* __restrict__ eta,
    float* __restrict__ ropeC, float* __restrict__ ropeS,
    int* __restrict__ esrc, int* __restrict__ edst)
{
  int idx = blockIdx.x * 256 + threadIdx.x;
  if (idx < NH_*HD_*17*R_){
    int r  = idx & 7;
    int k  = (idx >> 3) % 17;
    int hd = idx / 136;          // h*64 + d
    int d  = hd & 63, h = hd >> 6;
    int col = h*512 + r*64 + d;
    Wt[idx] = (k < 16) ? l2w[k*4096 + col] : l2b[col];
    return;
  }
  idx -= NH_*HD_*17*R_;
  if (idx < T_*L_){ eta[idx] = softplus_f(step[idx]); return; }
  idx -= T_*L_;
  if (idx < 9*32){
    int d = idx & 31, rel = (idx >> 5) - 4;
    float invf = expf(-((float)d / 32.f) * 9.210340371976184f);  // ln(10000)
    float ang = (float)rel * invf;
    ropeC[idx] = cosf(ang); ropeS[idx] = sinf(ang);
    return;
  }
  idx -= 9*32;
  if (idx < 2*8*L_){
    if (idx < 8*L_) esrc[idx] = -1; else edst[idx - 8*L_] = -1;
    return;
  }
}

// ---------------------------------------------------------------------------
// k_fill: scatter edge ids into per-node slot tables (unique (node,slot)).
// ---------------------------------------------------------------------------
__global__ __launch_bounds__(256) void k_fill(
    const int* __restrict__ ei, const int* __restrict__ ej, int E,
    int* __restrict__ esrc, int* __restrict__ edst)
{
  int e = blockIdx.x * 256 + threadIdx.x;
  if (e >= E) return;
  int i = ei[e], j = ej[e];
  int o = j - i;                      // in [-4,4] \ {0}
  int slot = (o < 0) ? (o + 4) : (o + 3);
  esrc[slot*L_ + i] = e;
  edst[slot*L_ + j] = e;
}

// ---------------------------------------------------------------------------
// k_te: u[(b*512 + n)*2048 + l] = x[b,l,:] @ te_w[:,n] + te_b[n]   (d-major u)
// ---------------------------------------------------------------------------
__global__ __launch_bounds__(256) void k_te(
    const float* __restrict__ x, const float* __restrict__ w,
    const float* __restrict__ bias, float* __restrict__ u)
{
  __shared__ float As[16][64];
  __shared__ float Bs[16][64];
  const int m0 = blockIdx.x * 64;
  const int n0 = blockIdx.y * 64;
  const int tid = threadIdx.x;
  const int ty = tid >> 4, tx = tid & 15;
  float acc[4][4] = {};
  for (int k0 = 0; k0 < 512; k0 += 16){
    {
      int m = tid >> 2, seg = tid & 3;
      float4 v = *(const float4*)(x + (size_t)(m0 + m)*512 + k0 + seg*4);
      As[seg*4+0][m] = v.x; As[seg*4+1][m] = v.y;
      As[seg*4+2][m] = v.z; As[seg*4+3][m] = v.w;
    }
    {
      int k = tid >> 4, c = (tid & 15)*4;
      float4 v = *(const float4*)(w + (size_t)(k0 + k)*512 + n0 + c);
      *(float4*)&Bs[k][c] = v;
    }
    __syncthreads();
    #pragma unroll
    for (int k = 0; k < 16; k++){
      float4 a = *(const float4*)(&As[k][ty*4]);
      float4 b = *(const float4*)(&Bs[k][tx*4]);
      float av[4] = {a.x, a.y, a.z, a.w};
      float bv[4] = {b.x, b.y, b.z, b.w};
      #pragma unroll
      for (int ii = 0; ii < 4; ii++)
        #pragma unroll
        for (int jj = 0; jj < 4; jj++)
          acc[ii][jj] = fmaf(av[ii], bv[jj], acc[ii][jj]);
    }
    __syncthreads();
  }
  const int bb = m0 >> 11;
  const int lb = (m0 & 2047) + ty*4;
  #pragma unroll
  for (int jj = 0; jj < 4; jj++){
    int n = n0 + tx*4 + jj;
    float bv = bias[n];
    float4 o;
    o.x = acc[0][jj] + bv; o.y = acc[1][jj] + bv;
    o.z = acc[2][jj] + bv; o.w = acc[3][jj] + bv;
    *(float4*)&u[((size_t)(bb*512 + n))*2048 + lb] = o;
  }
}

// ---------------------------------------------------------------------------
// k_pq: PQ[m][0:64] = x[m,:] @ [a1w_top | a1w_bot | l1w_top | l1w_bot]
//   cols 0-15 : x @ a1w[:512]   (P1)
//   cols 16-31: x @ a1w[512:]   (Q1)
//   cols 32-47: x @ l1w[:512]   (P2)
//   cols 48-63: x @ l1w[512:]   (Q2)
// m = b*2048 + l. Grid: (64,1), 256 threads, 64x64 tile.
// ---------------------------------------------------------------------------
__global__ __launch_bounds__(256) void k_pq(
    const float* __restrict__ x, const float* __restrict__ a1w,
    const float* __restrict__ l1w, float* __restrict__ PQ)
{
  __shared__ float As[16][64];
  __shared__ float Bs[16][64];
  const int m0 = blockIdx.x * 64;
  const int tid = threadIdx.x;
  const int ty = tid >> 4, tx = tid & 15;
  // B source for this thread's 4 columns (fixed across k0):
  const int c = (tid & 15) * 4;
  const int group = c >> 4;                 // 0..3
  const float* src = (group & 2) ? l1w : a1w;
  const int krow_off = (group & 1) ? 512 : 0;
  const int cc = c & 15;
  float acc[4][4] = {};
  for (int k0 = 0; k0 < 512; k0 += 16){
    {
      int m = tid >> 2, seg = tid & 3;
      float4 v = *(const float4*)(x + (size_t)(m0 + m)*512 + k0 + seg*4);
      As[seg*4+0][m] = v.x; As[seg*4+1][m] = v.y;
      As[seg*4+2][m] = v.z; As[seg*4+3][m] = v.w;
    }
    {
      int k = tid >> 4;
      float4 v = *(const float4*)(src + (size_t)(krow_off + k0 + k)*16 + cc);
      *(float4*)&Bs[k][c] = v;
    }
    __syncthreads();
    #pragma unroll
    for (int k = 0; k < 16; k++){
      float4 a = *(const float4*)(&As[k][ty*4]);
      float4 b = *(const float4*)(&Bs[k][tx*4]);
      float av[4] = {a.x, a.y, a.z, a.w};
      float bv[4] = {b.x, b.y, b.z, b.w};
      #pragma unroll
      for (int ii = 0; ii < 4; ii++)
        #pragma unroll
        for (int jj = 0; jj < 4; jj++)
          acc[ii][jj] = fmaf(av[ii], bv[jj], acc[ii][jj]);
    }
    __syncthreads();
  }
  #pragma unroll
  for (int ii = 0; ii < 4; ii++){
    int m = m0 + ty*4 + ii;
    float4 o;
    o.x = acc[ii][0]; o.y = acc[ii][1]; o.z = acc[ii][2]; o.w = acc[ii][3];
    *(float4*)&PQ[(size_t)m*64 + tx*4] = o;
  }
}

// ---------------------------------------------------------------------------
// k_feat2: per (b, edge): ha = P1[i]+Q1[j]+b1 -> gelu -> alpha
//                         hl = P2[i]+Q2[j]+b2 -> gelu -> h2
// ---------------------------------------------------------------------------
__global__ __launch_bounds__(256) void k_feat2(
    const float* __restrict__ PQ, const int* __restrict__ ei, const int* __restrict__ ej,
    const float* __restrict__ a1b, const float* __restrict__ a2w,
    const float* __restrict__ a2b, const float* __restrict__ l1b,
    int E, float* __restrict__ alphas, float* __restrict__ h2t)
{
  int e = blockIdx.x * 256 + threadIdx.x;
  int b = blockIdx.y;
  if (e >= E) return;
  int i = ei[e], j = ej[e];
  const float* Pi = PQ + ((size_t)b*L_ + i)*64;
  const float* Pj = PQ + ((size_t)b*L_ + j)*64;
  float ha[16], hl[16];
  #pragma unroll
  for (int q = 0; q < 4; q++){
    float4 p1 = *(const float4*)(Pi + q*4);        // P1
    float4 q1 = *(const float4*)(Pj + 16 + q*4);   // Q1
    float4 p2 = *(const float4*)(Pi + 32 + q*4);   // P2
    float4 q2 = *(const float4*)(Pj + 48 + q*4);   // Q2
    ha[q*4+0] = p1.x + q1.x; ha[q*4+1] = p1.y + q1.y;
    ha[q*4+2] = p1.z + q1.z; ha[q*4+3] = p1.w + q1.w;
    hl[q*4+0] = p2.x + q2.x; hl[q*4+1] = p2.y + q2.y;
    hl[q*4+2] = p2.z + q2.z; hl[q*4+3] = p2.w + q2.w;
  }
  float av = a2b[0];
  #pragma unroll
  for (int n = 0; n < 16; n++){
    float g = gelu_f(ha[n] + a1b[n]);
    av += g * a2w[n];
  }
  alphas[(size_t)b*E + e] = softplus_f(av);
  #pragma unroll
  for (int n = 0; n < 16; n++){
    float g = gelu_f(hl[n] + l1b[n]);
    h2t[((size_t)b*16 + n)*E + e] = g;
  }
}

// ---------------------------------------------------------------------------
// k_edge: per (b,h,edge) residual. Thread = edge; Λ rows recomputed from
// h2 (17x8 FMAs per d, wave-uniform W → s_loads). Pass1 accumulates S[r]
// (and row norms at t=0); pass2 recomputes lam and writes residuals.
// ---------------------------------------------------------------------------
template<int TZERO>
__global__ __launch_bounds__(256) void k_edge(
    const float* __restrict__ u, const float* __restrict__ Wt,
    const float* __restrict__ h2t, const float* __restrict__ alphas,
    const float* __restrict__ ropeC, const float* __restrict__ ropeS,
    const int* __restrict__ ei, const int* __restrict__ ej,
    int E, float* __restrict__ invn, float* __restrict__ res)
{
  int e = blockIdx.x * 256 + threadIdx.x;
  int bh = blockIdx.y;
  int b = bh >> 3, h = bh & 7;
  if (e >= E) return;
  int i = ei[e], j = ej[e];
  int ridx = (i - j) + 4;
  const float* cT = ropeC + ridx*32;
  const float* sT = ropeS + ridx*32;
  const float* ub = u + ((size_t)(b*512 + h*64))*2048;
  const float* Wh = Wt + (size_t)h*(64*136);
  float h2v[16];
  #pragma unroll
  for (int k = 0; k < 16; k++) h2v[k] = h2t[((size_t)b*16 + k)*E + e];

  float S[8] = {};
  float ss[8] = {};
  #pragma unroll 2
  for (int dp = 0; dp < 32; dp++){
    float ui0 = ub[dp*2048 + i];
    float ui1 = ub[(dp+32)*2048 + i];
    float uj0 = ub[dp*2048 + j];
    float uj1 = ub[(dp+32)*2048 + j];
    float c = cT[dp], s = sT[dp];
    float d0 = ui0*c - ui1*s - uj0;
    float d1 = ui1*c + ui0*s - uj1;
    const float* W0 = Wh + dp*136;
    const float* W1 = Wh + (dp+32)*136;
    float lam0[8], lam1[8];
    #pragma unroll
    for (int r = 0; r < 8; r++){ lam0[r] = W0[128+r]; lam1[r] = W1[128+r]; }
    #pragma unroll
    for (int k = 0; k < 16; k++){
      float hk = h2v[k];
      #pragma unroll
      for (int r = 0; r < 8; r++){
        lam0[r] = fmaf(W0[k*8+r], hk, lam0[r]);
        lam1[r] = fmaf(W1[k*8+r], hk, lam1[r]);
      }
    }
    #pragma unroll
    for (int r = 0; r < 8; r++){
      S[r] += lam0[r]*d0 + lam1[r]*d1;
      if (TZERO) ss[r] += lam0[r]*lam0[r] + lam1[r]*lam1[r];
    }
  }

  float alpha = alphas[(size_t)b*E + e];
  float coef[8];
  #pragma unroll
  for (int r = 0; r < 8; r++){
    float iv;
    if (TZERO){
      iv = 1.f / fmaxf(sqrtf(ss[r]), 1e-12f);
      invn[((size_t)bh*8 + r)*E + e] = iv;
    } else {
      iv = invn[((size_t)bh*8 + r)*E + e];
    }
    coef[r] = iv * iv * S[r];
  }

  float* rr = res + (size_t)bh*64*E;
  #pragma unroll 2
  for (int dp = 0; dp < 32; dp++){
    float ui0 = ub[dp*2048 + i];
    float ui1 = ub[(dp+32)*2048 + i];
    float uj0 = ub[dp*2048 + j];
    float uj1 = ub[(dp+32)*2048 + j];
    float c = cT[dp], s = sT[dp];
    float d0 = ui0*c - ui1*s - uj0;
    float d1 = ui1*c + ui0*s - uj1;
    const float* W0 = Wh + dp*136;
    const float* W1 = Wh + (dp+32)*136;
    float lam0[8], lam1[8];
    #pragma unroll
    for (int r = 0; r < 8; r++){ lam0[r] = W0[128+r]; lam1[r] = W1[128+r]; }
    #pragma unroll
    for (int k = 0; k < 16; k++){
      float hk = h2v[k];
      #pragma unroll
      for (int r = 0; r < 8; r++){
        lam0[r] = fmaf(W0[k*8+r], hk, lam0[r]);
        lam1[r] = fmaf(W1[k*8+r], hk, lam1[r]);
      }
    }
    float r0 = alpha*d0, r1 = alpha*d1;
    #pragma unroll
    for (int r = 0; r < 8; r++){
      r0 = fmaf(coef[r], lam0[r], r0);
      r1 = fmaf(coef[r], lam1[r], r1);
    }
    rr[(size_t)dp*E + e]       = r0;
    rr[(size_t)(dp+32)*E + e]  = r1;
  }
}

// ---------------------------------------------------------------------------
// k_upd: per node, gather +res over src edges, -res over dst edges, apply eta.
// ---------------------------------------------------------------------------
__global__ __launch_bounds__(256) void k_upd(
    int t, const float* __restrict__ res, const int* __restrict__ esrc,
    const int* __restrict__ edst, const float* __restrict__ eta,
    int E, float* __restrict__ u)
{
  int bh = blockIdx.y;
  int l  = blockIdx.x*64 + (threadIdx.x & 63);
  int dg = threadIdx.x >> 6;
  int es[8], ed[8];
  #pragma unroll
  for (int o = 0; o < 8; o++){ es[o] = esrc[o*L_ + l]; ed[o] = edst[o*L_ + l]; }
  float et = eta[t*L_ + l];
  const float* rr = res + (size_t)bh*64*E;
  float* ub = u + (size_t)bh*64*2048;
  for (int d = dg*16; d < dg*16 + 16; d++){
    const float* rd = rr + (size_t)d*E;
    float acc = 0.f;
    #pragma unroll
    for (int o = 0; o < 8; o++){
      float vs = (es[o] >= 0) ? rd[es[o]] : 0.f;
      float vd = (ed[o] >= 0) ? rd[ed[o]] : 0.f;
      acc += vs - vd;
    }
    ub[(size_t)d*2048 + l] -= et * acc;
  }
}

// ---------------------------------------------------------------------------
// k_out: out[b,l,n] = u[b,:,l] @ out_w[:,n] + out_b[n], f32 store.
// ---------------------------------------------------------------------------
__global__ __launch_bounds__(256) void k_out(
    const float* __restrict__ u, const float* __restrict__ w,
    const float* __restrict__ bias, float* __restrict__ outp)
{
  __shared__ float As[16][64];
  __shared__ float Bs[16][64];
  const int m0 = blockIdx.x * 64;
  const int n0 = blockIdx.y * 64;
  const int tid = threadIdx.x;
  const int ty = tid >> 4, tx = tid & 15;
  const int bb = m0 >> 11;
  const int l0 = m0 & 2047;
  float acc[4][4] = {};
  for (int k0 = 0; k0 < 512; k0 += 16){
    {
      int k = tid >> 4, ls = (tid & 15)*4;
      float4 v = *(const float4*)&u[((size_t)(bb*512 + k0 + k))*2048 + l0 + ls];
      *(float4*)&As[k][ls] = v;
    }
    {
      int k = tid >> 4, c = (tid & 15)*4;
      float4 v = *(const float4*)(w + (size_t)(k0 + k)*512 + n0 + c);
      *(float4*)&Bs[k][c] = v;
    }
    __syncthreads();
    #pragma unroll
    for (int k = 0; k < 16; k++){
      float4 a = *(const float4*)(&As[k][ty*4]);
      float4 b = *(const float4*)(&Bs[k][tx*4]);
      float av[4] = {a.x, a.y, a.z, a.w};
      float bv[4] = {b.x, b.y, b.z, b.w};
      #pragma unroll
      for (int ii = 0; ii < 4; ii++)
        #pragma unroll
        for (int jj = 0; jj < 4; jj++)
          acc[ii][jj] = fmaf(av[ii], bv[jj], acc[ii][jj]);
    }
    __syncthreads();
  }
  float bv[4];
  #pragma unroll
  for (int jj = 0; jj < 4; jj++) bv[jj] = bias[n0 + tx*4 + jj];
  #pragma unroll
  for (int ii = 0; ii < 4; ii++){
    int l = l0 + ty*4 + ii;
    float4 o;
    o.x = acc[ii][0] + bv[0];
    o.y = acc[ii][1] + bv[1];
    o.z = acc[ii][2] + bv[2];
    o.w = acc[ii][3] + bv[3];
    *(float4*)&outp[((size_t)(bb*2048 + l))*512 + n0 + tx*4] = o;
  }
}

// ---------------------------------------------------------------------------
extern "C" void kernel_launch(void* const* d_in, const int* in_sizes, int n_in,
                              void* d_out, int out_size, void* d_ws, size_t ws_size,
                              hipStream_t stream)
{
  const float* x    = (const float*)d_in[0];
  const int*   ei   = (const int*)d_in[1];
  const int*   ej   = (const int*)d_in[2];
  const float* tew  = (const float*)d_in[3];
  const float* teb  = (const float*)d_in[4];
  const float* a1w  = (const float*)d_in[5];
  const float* a1b  = (const float*)d_in[6];
  const float* a2w  = (const float*)d_in[7];
  const float* a2b  = (const float*)d_in[8];
  const float* l1w  = (const float*)d_in[9];
  const float* l1b  = (const float*)d_in[10];
  const float* l2w  = (const float*)d_in[11];
  const float* l2b  = (const float*)d_in[12];
  const float* step = (const float*)d_in[13];
  const float* ow   = (const float*)d_in[14];
  const float* ob   = (const float*)d_in[15];
  float* outp = (float*)d_out;
  const int E = in_sizes[1];

  char* p = (char*)d_ws;
  auto carve = [&](size_t nbytes)->char*{
    char* q = p; p += (nbytes + 255) & ~(size_t)255; return q;
  };
  float* u      = (float*)carve((size_t)B_*512*2048*4);     // d-major node states
  float* res    = (float*)carve((size_t)B_*NH_*64*E*4);     // per-edge residuals
  float* PQ     = (float*)carve((size_t)B_*L_*64*4);        // node projections
  float* h2t    = (float*)carve((size_t)B_*16*E*4);
  float* alphas = (float*)carve((size_t)B_*E*4);
  float* invn   = (float*)carve((size_t)B_*NH_*8*E*4);
  float* Wt     = (float*)carve((size_t)69632*4);
  float* eta    = (float*)carve((size_t)T_*L_*4);
  float* ropeC  = (float*)carve((size_t)288*4);
  float* ropeS  = (float*)carve((size_t)288*4);
  int*   esrc   = (int*)carve((size_t)8*L_*4);
  int*   edst   = (int*)carve((size_t)8*L_*4);

  k_misc<<<dim3(418), dim3(256), 0, stream>>>(l2w, l2b, step,
                                              Wt, eta, ropeC, ropeS, esrc, edst);
  k_fill<<<dim3((E + 255)/256), dim3(256), 0, stream>>>(ei, ej, E, esrc, edst);
  k_te<<<dim3(64, 8), dim3(256), 0, stream>>>(x, tew, teb, u);
  k_pq<<<dim3(64), dim3(256), 0, stream>>>(x, a1w, l1w, PQ);
  k_feat2<<<dim3((E + 255)/256, B_), dim3(256), 0, stream>>>(
      PQ, ei, ej, a1b, a2w, a2b, l1b, E, alphas, h2t);

  for (int t = 0; t < T_; t++){
    if (t == 0)
      k_edge<1><<<dim3((E + 255)/256, B_*NH_), dim3(256), 0, stream>>>(
          u, Wt, h2t, alphas, ropeC, ropeS, ei, ej, E, invn, res);
    else
      k_edge<0><<<dim3((E + 255)/256, B_*NH_), dim3(256), 0, stream>>>(
          u, Wt, h2t, alphas, ropeC, ropeS, ei, ej, E, invn, res);
    k_upd<<<dim3(L_/64, B_*NH_), dim3(256), 0, stream>>>(t, res, esrc, edst, eta, E, u);
  }

  k_out<<<dim3(64, 8), dim3(256), 0, stream>>>(u, ow, ob, outp);
}